// Round 22
// baseline (444.276 us; speedup 1.0000x reference)
//
#include <hip/hip_runtime.h>
#include <math.h>

#define NROWS 8192
#define DIM   64
#define KSEL  32
#define NQ    (NROWS - KSEL)   /* 8160 query rows */
#define P1LEN 512              /* pass-1 exact prefix */
#define CAP   1024             /* per-query candidate list capacity */
#define FILT_CB 256            /* candidates per filter block */
#define NMASK (NROWS / 16)     /* 512 bitmap words per query row */

typedef __attribute__((ext_vector_type(8))) short bf16x8;
typedef __attribute__((ext_vector_type(4))) float f32x4;

// ---------------------------------------------------------------------------
// Kernel A: row norms replicating XLA:CPU (LLVM-vectorized fused reduce):
//   VF=8 lanes, init 0, per-lane FMA chain, horizontal shuffle-tree
//   ((r0+r4)+(r2+r6)) + ((r1+r5)+(r3+r7)).   [validated bit-exact R8-R13]
// ---------------------------------------------------------------------------
__global__ void norms_kernel(const float* __restrict__ x, float* __restrict__ sq) {
    int j = blockIdx.x * blockDim.x + threadIdx.x;
    if (j >= NROWS) return;
    const float* xr = x + (size_t)j * DIM;
    float r[8];
#pragma unroll
    for (int u = 0; u < 8; ++u) r[u] = 0.0f;
#pragma unroll
    for (int i = 0; i < DIM; i += 8) {
#pragma unroll
        for (int u = 0; u < 8; ++u)
            r[u] = __fmaf_rn(xr[i + u], xr[i + u], r[u]);
    }
    const float s04 = __fadd_rn(r[0], r[4]);
    const float s26 = __fadd_rn(r[2], r[6]);
    const float s15 = __fadd_rn(r[1], r[5]);
    const float s37 = __fadd_rn(r[3], r[7]);
    sq[j] = __fadd_rn(__fadd_rn(s04, s26), __fadd_rn(s15, s37));
}

// ---------------------------------------------------------------------------
// Transpose x [8192][64] -> xT [64][8192] via LDS tile (64x64, +1 pad).
// Enables COALESCED candidate loads in pass1.
// ---------------------------------------------------------------------------
__global__ __launch_bounds__(256)
void transpose_kernel(const float* __restrict__ x, float* __restrict__ xT) {
    __shared__ float tile[64][65];
    const int jb  = blockIdx.x * 64;
    const int t   = threadIdx.x;
    const int row = t >> 2;                 // 0..63
    const int cb  = (t & 3) * 16;           // 0,16,32,48
    const float4* src = reinterpret_cast<const float4*>(
        x + (size_t)(jb + row) * DIM + cb);
#pragma unroll
    for (int i = 0; i < 4; ++i) {
        const float4 v = src[i];
        tile[row][cb + 4 * i + 0] = v.x; tile[row][cb + 4 * i + 1] = v.y;
        tile[row][cb + 4 * i + 2] = v.z; tile[row][cb + 4 * i + 3] = v.w;
    }
    __syncthreads();
    const int k = row;                      // dim index this thread writes
#pragma unroll
    for (int i = 0; i < 4; ++i) {
        float4 w;
        w.x = tile[cb + 4 * i + 0][k]; w.y = tile[cb + 4 * i + 1][k];
        w.z = tile[cb + 4 * i + 2][k]; w.w = tile[cb + 4 * i + 3][k];
        *reinterpret_cast<float4*>(xT + (size_t)k * NROWS + jb + cb + 4 * i) = w;
    }
}

// ---------------------------------------------------------------------------
// Convert x -> bf16 (RNE), 4 elems/thread.
// bf16 RNE rel-err <= 2^-8 per element -> rigorous filter margin (below).
// ---------------------------------------------------------------------------
__global__ __launch_bounds__(256)
void convert_kernel(const float* __restrict__ x, unsigned short* __restrict__ xb) {
    const int i = (blockIdx.x * blockDim.x + threadIdx.x) * 4;
    if (i >= NROWS * DIM) return;
    const float4 v = *reinterpret_cast<const float4*>(x + i);
    const float vv[4] = {v.x, v.y, v.z, v.w};
    unsigned short o[4];
#pragma unroll
    for (int u = 0; u < 4; ++u) {
        const unsigned b = __float_as_uint(vv[u]);
        o[u] = (unsigned short)((b + 0x7FFFu + ((b >> 16) & 1u)) >> 16);
    }
    *reinterpret_cast<ushort4*>(xb + i) = make_ushort4(o[0], o[1], o[2], o[3]);
}

// ---------------------------------------------------------------------------
// Pass 1 (v2, R11-validated): exact top-32 over prefix [0, min(512, r)).
// Coalesced xT candidate loads, 4 queries/block (one per wave).  Bit-exact
// chain preserved.  Selection: 8 keys/lane, 32 shuffle extract-min.
// ---------------------------------------------------------------------------
__global__ __launch_bounds__(256)
void pass1_kernel(const float* __restrict__ x, const float* __restrict__ xT,
                  const float* __restrict__ sq,
                  unsigned long long* __restrict__ tau0,
                  unsigned long long* __restrict__ lists) {
    const int wave = threadIdx.x >> 6;  // 0..3: independent query per wave
    const int lane = threadIdx.x & 63;
    const int qi   = blockIdx.x * 4 + wave;   // 0..8159
    const int r    = qi + KSEL;               // query row (wave-uniform)
    const int P    = min(r, P1LEN);

    const float* qp  = x + (size_t)r * DIM;   // uniform -> scalar loads
    const float  sqr = sq[r];

    float acc[8];
#pragma unroll
    for (int u = 0; u < 8; ++u) acc[u] = 0.0f;
    const float4* xT4 = reinterpret_cast<const float4*>(xT);
#pragma unroll 4
    for (int k = 0; k < DIM; ++k) {
        const float  qk = qp[k];
        const float4 c0 = xT4[(size_t)k * (NROWS / 4) + lane];       // j=4l..+3
        const float4 c1 = xT4[(size_t)k * (NROWS / 4) + 64 + lane];  // j=256+4l..+3
        acc[0] = __fmaf_rn(qk, c0.x, acc[0]);
        acc[1] = __fmaf_rn(qk, c0.y, acc[1]);
        acc[2] = __fmaf_rn(qk, c0.z, acc[2]);
        acc[3] = __fmaf_rn(qk, c0.w, acc[3]);
        acc[4] = __fmaf_rn(qk, c1.x, acc[4]);
        acc[5] = __fmaf_rn(qk, c1.y, acc[5]);
        acc[6] = __fmaf_rn(qk, c1.z, acc[6]);
        acc[7] = __fmaf_rn(qk, c1.w, acc[7]);
    }

    unsigned long long key[8];
    {
        const float4 sq0 = *reinterpret_cast<const float4*>(sq + 4 * lane);
        const float4 sq1 = *reinterpret_cast<const float4*>(sq + 256 + 4 * lane);
        const float sqc[8] = {sq0.x, sq0.y, sq0.z, sq0.w,
                              sq1.x, sq1.y, sq1.z, sq1.w};
#pragma unroll
        for (int u = 0; u < 8; ++u) {
            const int j = (u < 4) ? (4 * lane + u) : (256 + 4 * lane + (u - 4));
            const float dd = fmaxf(
                __fsub_rn(__fadd_rn(sqr, sqc[u]), __fmul_rn(2.0f, acc[u])), 0.0f);
            key[u] = (j < P)
                ? (((unsigned long long)__float_as_uint(dd) << 32) | (unsigned)j)
                : ~0ull;
        }
    }

    unsigned long long pmin = ~0ull;
#pragma unroll
    for (int s = 0; s < 8; ++s) pmin = key[s] < pmin ? key[s] : pmin;

    unsigned long long g = ~0ull;
    for (int it = 0; it < KSEL; ++it) {
        unsigned long long v = pmin;
#pragma unroll
        for (int off = 32; off > 0; off >>= 1) {
            const unsigned long long o = __shfl_down(v, off, 64);
            v = o < v ? o : v;
        }
        g = __shfl(v, 0, 64);
        if (lane == 0) lists[(size_t)qi * CAP + it] = g;
        if (pmin == g) {            // unique winner (keys embed unique j)
#pragma unroll
            for (int s = 0; s < 8; ++s) if (key[s] == g) key[s] = ~0ull;
            pmin = ~0ull;
#pragma unroll
            for (int s = 0; s < 8; ++s) pmin = key[s] < pmin ? key[s] : pmin;
        }
    }
    if (lane == 0) tau0[qi] = g;
}

// ---------------------------------------------------------------------------
// Filter (v11, R15-validated): bf16 MFMA screen -> BITMAP, no atomics.
// Each (query r, 16-cand group j0) accept mask is owned by exactly one
// 16-lane slice -> fire-and-forget 2-B store of bm[r][j0>>4].  Rigorous
// margin 1.5*2^-7*S (R9/R13-validated).
// ---------------------------------------------------------------------------
__global__ __launch_bounds__(256)
void filter_kernel(const unsigned short* __restrict__ xb,
                   const float* __restrict__ sq,
                   const unsigned long long* __restrict__ tau0,
                   unsigned short* __restrict__ bm) {
    const int qb   = blockIdx.x;                        // 64-query tile
    const int jb   = P1LEN + blockIdx.y * FILT_CB;      // candidate tile base
    const int r_hi = min(KSEL + (qb + 1) * 64, NROWS);  // exclusive query cap
    if (jb >= r_hi) return;                             // uniform exit

    const int wave = threadIdx.x >> 6;                  // 0..3
    const int lane = threadIdx.x & 63;
    const int rb   = KSEL + qb * 64 + wave * 16;        // wave's first q row
    const int col  = lane & 15;
    const int kg   = lane >> 4;                         // k-group 0..3

    // A fragments (row rb+col, k = kg*8 + {0..7} and +32): contiguous 16B
    const int arow = min(rb + col, NROWS - 1);
    const bf16x8 a0 = *reinterpret_cast<const bf16x8*>(xb + (size_t)arow * DIM + kg * 8);
    const bf16x8 a1 = *reinterpret_cast<const bf16x8*>(xb + (size_t)arow * DIM + 32 + kg * 8);

    // Epilogue per-lane row data: D rows rb + kg*4 + i
    float sqr[4], thm[4]; int rr[4];
#pragma unroll
    for (int i = 0; i < 4; ++i) {
        const int r = rb + kg * 4 + i;
        rr[i]  = r;
        const int rc = min(r, NROWS - 1);
        sqr[i] = sq[rc];
        thm[i] = (r < NROWS) ? __uint_as_float((unsigned)(tau0[r - KSEL] >> 32))
                             : -1.0f;                   // reject all
    }

    for (int sub = 0; sub < FILT_CB / 16; ++sub) {
        const int j0 = jb + sub * 16;
        if (j0 >= r_hi) break;                          // wave-uniform
        const int j  = j0 + col;
        const int jc = min(j, NROWS - 1);
        const bf16x8 b0 = *reinterpret_cast<const bf16x8*>(xb + (size_t)jc * DIM + kg * 8);
        const bf16x8 b1 = *reinterpret_cast<const bf16x8*>(xb + (size_t)jc * DIM + 32 + kg * 8);
        f32x4 acc = {0.f, 0.f, 0.f, 0.f};
        acc = __builtin_amdgcn_mfma_f32_16x16x32_bf16(a0, b0, acc, 0, 0, 0);
        acc = __builtin_amdgcn_mfma_f32_16x16x32_bf16(a1, b1, acc, 0, 0, 0);
        const float sqc = sq[jc];
#pragma unroll
        for (int i = 0; i < 4; ++i) {
            const float s = __fadd_rn(sqr[i], sqc);
            const float d = __fmaf_rn(-2.0f, acc[i], s);
            const bool accept = (j < rr[i]) &&
                                (d <= __fmaf_rn(0.01171875f, s, thm[i]));
            const unsigned long long mask = __ballot(accept);
            const unsigned slice = (unsigned)((mask >> (kg * 16)) & 0xFFFFull);
            if (col == 0 && rr[i] < NROWS)              // one writer per word
                bm[(size_t)rr[i] * NMASK + (j0 >> 4)] = (unsigned short)slice;
        }
    }
}

// ---------------------------------------------------------------------------
// Refine+Merge (v9): serial-scalar costs removed.
// R21 POST-MORTEM: depth-2 interleave materialized (VGPR 32->44) but dur
// unchanged -> Phase B is L1-TRANSACTION bound, not exposed-latency bound.
// Remaining serial costs per block: ~360 same-address LDS atomics (~7Kcy)
// and a single-wave 32-iter x 16-slot-rescan extract-min (~5Kcy).  v9:
//   Phase A: per-wave PREFIX-SUM allocation -- popcount own bitmap words,
//            shfl_up scan, ONE atomic per wave, write own bits to range.
//   Phase B: ballot-aggregated appends (R9 pattern): one atomic per
//            wave-round; rounds block-uniform; depth-2 dropped (null).
//   Phase C: TWO-STAGE -- both waves extract top-32 of their half (8
//            slots/lane) into semi[64]; wave 0 finals over 64 keys
//            (1 slot/lane, trivial rescan).  top32(A u B) ==
//            top32(top32(A) u top32(B)); u64 keys unique -> identical out.
// Chains unchanged: exact VALIDATED fp32 k=0..63 ascending, float4 x/y/z/w.
// ---------------------------------------------------------------------------
__global__ __launch_bounds__(128)
void refine_merge_kernel(const float* __restrict__ x, const float* __restrict__ sq,
                         const unsigned long long* __restrict__ tau0,
                         const unsigned short* __restrict__ bm,
                         const unsigned long long* __restrict__ lists,
                         float* __restrict__ out_d, float* __restrict__ out_i) {
    __shared__ unsigned long long keys[CAP];
    __shared__ unsigned long long semi[2 * KSEL];
    __shared__ unsigned short jlist[CAP];
    __shared__ unsigned jcnt_s, lcnt;
    const int qi  = blockIdx.x;               // 0..8159, one query per block
    const int r   = qi + KSEL;
    const int tid = threadIdx.x;
    const int ln  = tid & 63;                 // lane within wave
    if (tid == 0) { jcnt_s = 0; lcnt = KSEL; }
    if (tid < KSEL) keys[tid] = lists[(size_t)qi * CAP + tid];  // pass1 keys
    __syncthreads();

    // ---- Phase A: prefix-sum compaction of accepted candidate indices
    const int mlast = (r - 1) >> 4;           // masks m in [32, mlast]
    unsigned ww[4];
#pragma unroll
    for (int s = 0; s < 4; ++s) {
        const int m = (P1LEN / 16) + tid + s * 128;
        ww[s] = (m <= mlast) ? (unsigned)bm[(size_t)r * NMASK + m] : 0u;
    }
    {
        const unsigned cnt = (unsigned)(__popc(ww[0]) + __popc(ww[1]) +
                                        __popc(ww[2]) + __popc(ww[3]));
        unsigned pre = cnt;                   // inclusive wave prefix sum
#pragma unroll
        for (int off = 1; off < 64; off <<= 1) {
            const unsigned o = __shfl_up(pre, off, 64);
            if (ln >= off) pre += o;
        }
        const unsigned total = __shfl(pre, 63, 64);
        unsigned base = 0;
        if (ln == 63 && total) base = atomicAdd(&jcnt_s, total);  // 1/wave
        base = __shfl(base, 63, 64);
        unsigned pos = base + pre - cnt;      // exclusive start
#pragma unroll
        for (int s = 0; s < 4; ++s) {
            unsigned msk = ww[s];
            const int m = (P1LEN / 16) + tid + s * 128;
            while (msk) {
                const int b = __builtin_ctz(msk);
                msk &= msk - 1;
                if (pos < CAP) jlist[pos] = (unsigned short)((m << 4) + b);
                ++pos;
            }
        }
    }
    __syncthreads();

    // ---- Phase B: exact chains, ballot-aggregated appends (1 atomic/round)
    const unsigned jcnt = min(jcnt_s, (unsigned)CAP);
    const unsigned th = (unsigned)(tau0[qi] >> 32);
    const float* qp = x + (size_t)r * DIM;    // block-uniform -> scalar loads
    const float  sqr = sq[r];
    const int rounds = (int)((jcnt + 127) >> 7);
    for (int rd = 0; rd < rounds; ++rd) {
        const unsigned idx = (unsigned)rd * 128 + (unsigned)tid;
        const bool valid = (idx < jcnt);
        const int j = valid ? (int)jlist[idx] : 0;
        const float4* cp4 = reinterpret_cast<const float4*>(x + (size_t)j * DIM);
        float acc = 0.0f;
#pragma unroll
        for (int k = 0; k < 16; ++k) {
            const float4 c = cp4[k];
            acc = __fmaf_rn(qp[4 * k + 0], c.x, acc);
            acc = __fmaf_rn(qp[4 * k + 1], c.y, acc);
            acc = __fmaf_rn(qp[4 * k + 2], c.z, acc);
            acc = __fmaf_rn(qp[4 * k + 3], c.w, acc);
        }
        const float dd = fmaxf(
            __fsub_rn(__fadd_rn(sqr, sq[j]), __fmul_rn(2.0f, acc)), 0.0f);
        const unsigned bits = __float_as_uint(dd);
        const bool keep = valid && (bits <= th);
        const unsigned long long mask = __ballot(keep);   // this wave's 64
        if (mask) {
            const int leader = __builtin_ctzll(mask);
            unsigned base = 0;
            if (ln == leader)
                base = atomicAdd(&lcnt, (unsigned)__popcll(mask)); // 1/wave
            base = __shfl(base, leader, 64);
            if (keep) {
                const unsigned slot =
                    base + (unsigned)__popcll(mask & ((1ull << ln) - 1ull));
                if (slot < CAP)
                    keys[slot] = ((unsigned long long)bits << 32) | (unsigned)j;
            }
        }
    }
    __syncthreads();

    // ---- Phase C stage 1: each wave extracts top-32 of its half -> semi
    const int ne = min((int)lcnt, CAP);
    {
        const int wv = tid >> 6;
        unsigned long long k[8];
#pragma unroll
        for (int s = 0; s < 8; ++s) {
            const int i2 = wv * 64 + ln + s * 128;
            k[s] = (i2 < ne) ? keys[i2] : ~0ull;
        }
        unsigned long long pmin = ~0ull;
#pragma unroll
        for (int s = 0; s < 8; ++s) pmin = k[s] < pmin ? k[s] : pmin;

        for (int it = 0; it < KSEL; ++it) {
            unsigned long long v = pmin;
#pragma unroll
            for (int off = 32; off > 0; off >>= 1) {
                const unsigned long long o = __shfl_down(v, off, 64);
                v = o < v ? o : v;
            }
            const unsigned long long g = __shfl(v, 0, 64);
            if (ln == 0) semi[wv * KSEL + it] = g;
            if (pmin == g) {        // unique winner rescans its registers
#pragma unroll
                for (int s = 0; s < 8; ++s) if (k[s] == g) k[s] = ~0ull;
                pmin = ~0ull;
#pragma unroll
                for (int s = 0; s < 8; ++s) pmin = k[s] < pmin ? k[s] : pmin;
            }
        }
    }
    __syncthreads();

    // ---- Phase C stage 2: wave 0 finals over the 64 semifinal keys
    if (tid >= 64) return;
    unsigned long long kk = semi[tid];        // 1 key/lane
    for (int it = 0; it < KSEL; ++it) {
        unsigned long long v = kk;
#pragma unroll
        for (int off = 32; off > 0; off >>= 1) {
            const unsigned long long o = __shfl_down(v, off, 64);
            v = o < v ? o : v;
        }
        const unsigned long long g = __shfl(v, 0, 64);
        if (tid == 0) {
            out_d[(size_t)qi * KSEL + it] = __uint_as_float((unsigned)(g >> 32));
            out_i[(size_t)qi * KSEL + it] = (float)(unsigned)(g & 0xFFFFFFFFu);
        }
        if (kk == g) kk = ~0ull;              // trivial invalidation
    }
}

extern "C" void kernel_launch(void* const* d_in, const int* in_sizes, int n_in,
                              void* d_out, int out_size, void* d_ws, size_t ws_size,
                              hipStream_t stream) {
    const float* x = (const float*)d_in[0];    // anchor_x [8192, 64] fp32
    float* sq = (float*)d_ws;                                        // 32 KB
    unsigned long long* tau0 =
        (unsigned long long*)((char*)d_ws + 32768);                  // 64 KB
    unsigned long long* lists =
        (unsigned long long*)((char*)d_ws + 131072);                 // 66.8 MB
    unsigned short* xb =
        (unsigned short*)((char*)d_ws + 66977792);                   // 1 MB bf16
    float* xT = (float*)((char*)d_ws + 68026368);                    // 2 MB fp32
    unsigned short* bm =
        (unsigned short*)((char*)d_ws + 70123520);                   // 8 MB bitmap
    float* out_d = (float*)d_out;              // [8160, 32] distances
    float* out_i = out_d + (size_t)NQ * KSEL;  // [8160, 32] indices (as fp32)

    norms_kernel<<<NROWS / 256, 256, 0, stream>>>(x, sq);
    transpose_kernel<<<NROWS / 64, 256, 0, stream>>>(x, xT);
    convert_kernel<<<NROWS * DIM / 1024, 256, 0, stream>>>(x, xb);
    pass1_kernel<<<NQ / 4, 256, 0, stream>>>(x, xT, sq, tau0, lists);
    dim3 gf(128, (NROWS - P1LEN) / FILT_CB);   // (query tile, candidate tile)
    filter_kernel<<<gf, 256, 0, stream>>>(xb, sq, tau0, bm);
    refine_merge_kernel<<<NQ, 128, 0, stream>>>(x, sq, tau0, bm, lists,
                                                out_d, out_i);
}

// Round 24
// 284.777 us; speedup vs baseline: 1.5601x; 1.5601x over previous
//
#include <hip/hip_runtime.h>
#include <math.h>

#define NROWS 8192
#define DIM   64
#define KSEL  32
#define NQ    (NROWS - KSEL)   /* 8160 query rows */
#define P1LEN 512              /* pass-1 exact prefix (256 FAILED: survivor
                                  count scales LINEARLY ~32*(r-P)/P -> CAP
                                  overflow at 256; 512 is the safe optimum) */
#define CAP   1024             /* per-query candidate list capacity */
#define FILT_CB 256            /* candidates per filter block */
#define NMASK (NROWS / 16)     /* 512 bitmap words per query row */

typedef __attribute__((ext_vector_type(8))) short bf16x8;
typedef __attribute__((ext_vector_type(4))) float f32x4;

// ---------------------------------------------------------------------------
// Kernel A: row norms replicating XLA:CPU (LLVM-vectorized fused reduce):
//   VF=8 lanes, init 0, per-lane FMA chain, horizontal shuffle-tree
//   ((r0+r4)+(r2+r6)) + ((r1+r5)+(r3+r7)).   [validated bit-exact R8-R13]
// ---------------------------------------------------------------------------
__global__ void norms_kernel(const float* __restrict__ x, float* __restrict__ sq) {
    int j = blockIdx.x * blockDim.x + threadIdx.x;
    if (j >= NROWS) return;
    const float* xr = x + (size_t)j * DIM;
    float r[8];
#pragma unroll
    for (int u = 0; u < 8; ++u) r[u] = 0.0f;
#pragma unroll
    for (int i = 0; i < DIM; i += 8) {
#pragma unroll
        for (int u = 0; u < 8; ++u)
            r[u] = __fmaf_rn(xr[i + u], xr[i + u], r[u]);
    }
    const float s04 = __fadd_rn(r[0], r[4]);
    const float s26 = __fadd_rn(r[2], r[6]);
    const float s15 = __fadd_rn(r[1], r[5]);
    const float s37 = __fadd_rn(r[3], r[7]);
    sq[j] = __fadd_rn(__fadd_rn(s04, s26), __fadd_rn(s15, s37));
}

// ---------------------------------------------------------------------------
// Transpose x [8192][64] -> xT [64][8192] via LDS tile (64x64, +1 pad).
// Enables COALESCED candidate loads in pass1.
// ---------------------------------------------------------------------------
__global__ __launch_bounds__(256)
void transpose_kernel(const float* __restrict__ x, float* __restrict__ xT) {
    __shared__ float tile[64][65];
    const int jb  = blockIdx.x * 64;
    const int t   = threadIdx.x;
    const int row = t >> 2;                 // 0..63
    const int cb  = (t & 3) * 16;           // 0,16,32,48
    const float4* src = reinterpret_cast<const float4*>(
        x + (size_t)(jb + row) * DIM + cb);
#pragma unroll
    for (int i = 0; i < 4; ++i) {
        const float4 v = src[i];
        tile[row][cb + 4 * i + 0] = v.x; tile[row][cb + 4 * i + 1] = v.y;
        tile[row][cb + 4 * i + 2] = v.z; tile[row][cb + 4 * i + 3] = v.w;
    }
    __syncthreads();
    const int k = row;                      // dim index this thread writes
#pragma unroll
    for (int i = 0; i < 4; ++i) {
        float4 w;
        w.x = tile[cb + 4 * i + 0][k]; w.y = tile[cb + 4 * i + 1][k];
        w.z = tile[cb + 4 * i + 2][k]; w.w = tile[cb + 4 * i + 3][k];
        *reinterpret_cast<float4*>(xT + (size_t)k * NROWS + jb + cb + 4 * i) = w;
    }
}

// ---------------------------------------------------------------------------
// Convert x -> bf16 (RNE), 4 elems/thread.
// bf16 RNE rel-err <= 2^-8 per element -> rigorous filter margin (below).
// ---------------------------------------------------------------------------
__global__ __launch_bounds__(256)
void convert_kernel(const float* __restrict__ x, unsigned short* __restrict__ xb) {
    const int i = (blockIdx.x * blockDim.x + threadIdx.x) * 4;
    if (i >= NROWS * DIM) return;
    const float4 v = *reinterpret_cast<const float4*>(x + i);
    const float vv[4] = {v.x, v.y, v.z, v.w};
    unsigned short o[4];
#pragma unroll
    for (int u = 0; u < 4; ++u) {
        const unsigned b = __float_as_uint(vv[u]);
        o[u] = (unsigned short)((b + 0x7FFFu + ((b >> 16) & 1u)) >> 16);
    }
    *reinterpret_cast<ushort4*>(xb + i) = make_ushort4(o[0], o[1], o[2], o[3]);
}

// ---------------------------------------------------------------------------
// Pass 1 (v2, R11-validated): exact top-32 over prefix [0, min(512, r)).
// Coalesced xT candidate loads, 4 queries/block (one per wave).  Bit-exact
// chain preserved.  Selection: 8 keys/lane, 32 shuffle extract-min.
// ---------------------------------------------------------------------------
__global__ __launch_bounds__(256)
void pass1_kernel(const float* __restrict__ x, const float* __restrict__ xT,
                  const float* __restrict__ sq,
                  unsigned long long* __restrict__ tau0,
                  unsigned long long* __restrict__ lists) {
    const int wave = threadIdx.x >> 6;  // 0..3: independent query per wave
    const int lane = threadIdx.x & 63;
    const int qi   = blockIdx.x * 4 + wave;   // 0..8159
    const int r    = qi + KSEL;               // query row (wave-uniform)
    const int P    = min(r, P1LEN);

    const float* qp  = x + (size_t)r * DIM;   // uniform -> scalar loads
    const float  sqr = sq[r];

    float acc[8];
#pragma unroll
    for (int u = 0; u < 8; ++u) acc[u] = 0.0f;
    const float4* xT4 = reinterpret_cast<const float4*>(xT);
#pragma unroll 4
    for (int k = 0; k < DIM; ++k) {
        const float  qk = qp[k];
        const float4 c0 = xT4[(size_t)k * (NROWS / 4) + lane];       // j=4l..+3
        const float4 c1 = xT4[(size_t)k * (NROWS / 4) + 64 + lane];  // j=256+4l..+3
        acc[0] = __fmaf_rn(qk, c0.x, acc[0]);
        acc[1] = __fmaf_rn(qk, c0.y, acc[1]);
        acc[2] = __fmaf_rn(qk, c0.z, acc[2]);
        acc[3] = __fmaf_rn(qk, c0.w, acc[3]);
        acc[4] = __fmaf_rn(qk, c1.x, acc[4]);
        acc[5] = __fmaf_rn(qk, c1.y, acc[5]);
        acc[6] = __fmaf_rn(qk, c1.z, acc[6]);
        acc[7] = __fmaf_rn(qk, c1.w, acc[7]);
    }

    unsigned long long key[8];
    {
        const float4 sq0 = *reinterpret_cast<const float4*>(sq + 4 * lane);
        const float4 sq1 = *reinterpret_cast<const float4*>(sq + 256 + 4 * lane);
        const float sqc[8] = {sq0.x, sq0.y, sq0.z, sq0.w,
                              sq1.x, sq1.y, sq1.z, sq1.w};
#pragma unroll
        for (int u = 0; u < 8; ++u) {
            const int j = (u < 4) ? (4 * lane + u) : (256 + 4 * lane + (u - 4));
            const float dd = fmaxf(
                __fsub_rn(__fadd_rn(sqr, sqc[u]), __fmul_rn(2.0f, acc[u])), 0.0f);
            key[u] = (j < P)
                ? (((unsigned long long)__float_as_uint(dd) << 32) | (unsigned)j)
                : ~0ull;
        }
    }

    unsigned long long pmin = ~0ull;
#pragma unroll
    for (int s = 0; s < 8; ++s) pmin = key[s] < pmin ? key[s] : pmin;

    unsigned long long g = ~0ull;
    for (int it = 0; it < KSEL; ++it) {
        unsigned long long v = pmin;
#pragma unroll
        for (int off = 32; off > 0; off >>= 1) {
            const unsigned long long o = __shfl_down(v, off, 64);
            v = o < v ? o : v;
        }
        g = __shfl(v, 0, 64);
        if (lane == 0) lists[(size_t)qi * CAP + it] = g;
        if (pmin == g) {            // unique winner (keys embed unique j)
#pragma unroll
            for (int s = 0; s < 8; ++s) if (key[s] == g) key[s] = ~0ull;
            pmin = ~0ull;
#pragma unroll
            for (int s = 0; s < 8; ++s) pmin = key[s] < pmin ? key[s] : pmin;
        }
    }
    if (lane == 0) tau0[qi] = g;
}

// ---------------------------------------------------------------------------
// Filter (v11, R15-validated): bf16 MFMA screen -> BITMAP, no atomics.
// Each (query r, 16-cand group j0) accept mask is owned by exactly one
// 16-lane slice -> fire-and-forget 2-B store of bm[r][j0>>4].  Rigorous
// margin 1.5*2^-7*S (R9/R13-validated).
// ---------------------------------------------------------------------------
__global__ __launch_bounds__(256)
void filter_kernel(const unsigned short* __restrict__ xb,
                   const float* __restrict__ sq,
                   const unsigned long long* __restrict__ tau0,
                   unsigned short* __restrict__ bm) {
    const int qb   = blockIdx.x;                        // 64-query tile
    const int jb   = P1LEN + blockIdx.y * FILT_CB;      // candidate tile base
    const int r_hi = min(KSEL + (qb + 1) * 64, NROWS);  // exclusive query cap
    if (jb >= r_hi) return;                             // uniform exit

    const int wave = threadIdx.x >> 6;                  // 0..3
    const int lane = threadIdx.x & 63;
    const int rb   = KSEL + qb * 64 + wave * 16;        // wave's first q row
    const int col  = lane & 15;
    const int kg   = lane >> 4;                         // k-group 0..3

    // A fragments (row rb+col, k = kg*8 + {0..7} and +32): contiguous 16B
    const int arow = min(rb + col, NROWS - 1);
    const bf16x8 a0 = *reinterpret_cast<const bf16x8*>(xb + (size_t)arow * DIM + kg * 8);
    const bf16x8 a1 = *reinterpret_cast<const bf16x8*>(xb + (size_t)arow * DIM + 32 + kg * 8);

    // Epilogue per-lane row data: D rows rb + kg*4 + i
    float sqr[4], thm[4]; int rr[4];
#pragma unroll
    for (int i = 0; i < 4; ++i) {
        const int r = rb + kg * 4 + i;
        rr[i]  = r;
        const int rc = min(r, NROWS - 1);
        sqr[i] = sq[rc];
        thm[i] = (r < NROWS) ? __uint_as_float((unsigned)(tau0[r - KSEL] >> 32))
                             : -1.0f;                   // reject all
    }

    for (int sub = 0; sub < FILT_CB / 16; ++sub) {
        const int j0 = jb + sub * 16;
        if (j0 >= r_hi) break;                          // wave-uniform
        const int j  = j0 + col;
        const int jc = min(j, NROWS - 1);
        const bf16x8 b0 = *reinterpret_cast<const bf16x8*>(xb + (size_t)jc * DIM + kg * 8);
        const bf16x8 b1 = *reinterpret_cast<const bf16x8*>(xb + (size_t)jc * DIM + 32 + kg * 8);
        f32x4 acc = {0.f, 0.f, 0.f, 0.f};
        acc = __builtin_amdgcn_mfma_f32_16x16x32_bf16(a0, b0, acc, 0, 0, 0);
        acc = __builtin_amdgcn_mfma_f32_16x16x32_bf16(a1, b1, acc, 0, 0, 0);
        const float sqc = sq[jc];
#pragma unroll
        for (int i = 0; i < 4; ++i) {
            const float s = __fadd_rn(sqr[i], sqc);
            const float d = __fmaf_rn(-2.0f, acc[i], s);
            const bool accept = (j < rr[i]) &&
                                (d <= __fmaf_rn(0.01171875f, s, thm[i]));
            const unsigned long long mask = __ballot(accept);
            const unsigned slice = (unsigned)((mask >> (kg * 16)) & 0xFFFFull);
            if (col == 0 && rr[i] < NROWS)              // one writer per word
                bm[(size_t)rr[i] * NMASK + (j0 >> 4)] = (unsigned short)slice;
        }
    }
}

// ---------------------------------------------------------------------------
// Refine+Merge (v6 VERBATIM, R19-measured best: 125us kernel, 284us total).
// R20 LJF hurt; R21 depth-2 null; R22 prefix-sum + two-stage hurt; R23
// P1LEN=256 overflowed CAP.  v6 is the plateau for this decomposition:
// Phase A bitmap->jlist compact (ctz + LDS atomic), Phase B balanced exact
// fp32 chains (k=0..63 ascending, float4 x/y/z/w, bit-exact), Phase C
// wave-0 16-keys/lane extract-min.
// ---------------------------------------------------------------------------
__global__ __launch_bounds__(128)
void refine_merge_kernel(const float* __restrict__ x, const float* __restrict__ sq,
                         const unsigned long long* __restrict__ tau0,
                         const unsigned short* __restrict__ bm,
                         const unsigned long long* __restrict__ lists,
                         float* __restrict__ out_d, float* __restrict__ out_i) {
    __shared__ unsigned long long keys[CAP];
    __shared__ unsigned short jlist[CAP];
    __shared__ unsigned jcnt_s, lcnt;
    const int qi  = blockIdx.x;               // 0..8159, one query per block
    const int r   = qi + KSEL;
    const int tid = threadIdx.x;
    if (tid == 0) { jcnt_s = 0; lcnt = KSEL; }
    if (tid < KSEL) keys[tid] = lists[(size_t)qi * CAP + tid];  // pass1 keys
    __syncthreads();

    // ---- Phase A: compact accepted candidate indices into jlist
    const int mlast = (r - 1) >> 4;           // masks m in [P1LEN/16, mlast]
    for (int m = (P1LEN / 16) + tid; m <= mlast; m += 128) {
        unsigned msk = bm[(size_t)r * NMASK + m];
        while (msk) {
            const int b = __builtin_ctz(msk);
            msk &= msk - 1;
            const unsigned slot = atomicAdd(&jcnt_s, 1u);     // LDS atomic
            if (slot < CAP) jlist[slot] = (unsigned short)((m << 4) + b);
        }
    }
    __syncthreads();

    // ---- Phase B: balanced exact chains over the compacted list
    const unsigned jcnt = min(jcnt_s, (unsigned)CAP);
    const unsigned th = (unsigned)(tau0[qi] >> 32);
    const float* qp = x + (size_t)r * DIM;    // block-uniform -> scalar loads
    const float  sqr = sq[r];
    for (unsigned idx = tid; idx < jcnt; idx += 128) {
        const int j = (int)jlist[idx];
        const float4* cp4 = reinterpret_cast<const float4*>(x + (size_t)j * DIM);
        float4 c[16];
#pragma unroll
        for (int k = 0; k < 16; ++k) c[k] = cp4[k];
        float acc = 0.0f;
#pragma unroll
        for (int k = 0; k < 16; ++k) {
            acc = __fmaf_rn(qp[4 * k + 0], c[k].x, acc);
            acc = __fmaf_rn(qp[4 * k + 1], c[k].y, acc);
            acc = __fmaf_rn(qp[4 * k + 2], c[k].z, acc);
            acc = __fmaf_rn(qp[4 * k + 3], c[k].w, acc);
        }
        const float dd = fmaxf(
            __fsub_rn(__fadd_rn(sqr, sq[j]), __fmul_rn(2.0f, acc)), 0.0f);
        const unsigned bits = __float_as_uint(dd);
        if (bits <= th) {
            const unsigned slot = atomicAdd(&lcnt, 1u);       // LDS atomic
            if (slot < CAP)
                keys[slot] = ((unsigned long long)bits << 32) | (unsigned)j;
        }
    }
    __syncthreads();

    // ---- Phase C: wave 0 extract-min (validated 16-keys/lane structure)
    if (tid >= 64) return;
    const int lane = tid;
    const int ne   = min((int)lcnt, CAP);

    unsigned long long k[16];
#pragma unroll
    for (int s = 0; s < 16; ++s) {
        const int idx = lane + (s << 6);
        k[s] = (idx < ne) ? keys[idx] : ~0ull;
    }
    unsigned long long pmin = ~0ull;
#pragma unroll
    for (int s = 0; s < 16; ++s) pmin = k[s] < pmin ? k[s] : pmin;

    for (int it = 0; it < KSEL; ++it) {
        unsigned long long v = pmin;
#pragma unroll
        for (int off = 32; off > 0; off >>= 1) {
            const unsigned long long o = __shfl_down(v, off, 64);
            v = o < v ? o : v;
        }
        const unsigned long long g = __shfl(v, 0, 64);
        if (lane == 0) {
            out_d[(size_t)qi * KSEL + it] = __uint_as_float((unsigned)(g >> 32));
            out_i[(size_t)qi * KSEL + it] = (float)(unsigned)(g & 0xFFFFFFFFu);
        }
        if (pmin == g) {            // unique winner rescans its registers
#pragma unroll
            for (int s = 0; s < 16; ++s) if (k[s] == g) k[s] = ~0ull;
            pmin = ~0ull;
#pragma unroll
            for (int s = 0; s < 16; ++s) pmin = k[s] < pmin ? k[s] : pmin;
        }
    }
}

extern "C" void kernel_launch(void* const* d_in, const int* in_sizes, int n_in,
                              void* d_out, int out_size, void* d_ws, size_t ws_size,
                              hipStream_t stream) {
    const float* x = (const float*)d_in[0];    // anchor_x [8192, 64] fp32
    float* sq = (float*)d_ws;                                        // 32 KB
    unsigned long long* tau0 =
        (unsigned long long*)((char*)d_ws + 32768);                  // 64 KB
    unsigned long long* lists =
        (unsigned long long*)((char*)d_ws + 131072);                 // 66.8 MB
    unsigned short* xb =
        (unsigned short*)((char*)d_ws + 66977792);                   // 1 MB bf16
    float* xT = (float*)((char*)d_ws + 68026368);                    // 2 MB fp32
    unsigned short* bm =
        (unsigned short*)((char*)d_ws + 70123520);                   // 8 MB bitmap
    float* out_d = (float*)d_out;              // [8160, 32] distances
    float* out_i = out_d + (size_t)NQ * KSEL;  // [8160, 32] indices (as fp32)

    norms_kernel<<<NROWS / 256, 256, 0, stream>>>(x, sq);
    transpose_kernel<<<NROWS / 64, 256, 0, stream>>>(x, xT);
    convert_kernel<<<NROWS * DIM / 1024, 256, 0, stream>>>(x, xb);
    pass1_kernel<<<NQ / 4, 256, 0, stream>>>(x, xT, sq, tau0, lists);
    dim3 gf(128, (NROWS - P1LEN) / FILT_CB);   // (query tile, candidate tile)
    filter_kernel<<<gf, 256, 0, stream>>>(xb, sq, tau0, bm);
    refine_merge_kernel<<<NQ, 128, 0, stream>>>(x, sq, tau0, bm, lists,
                                                out_d, out_i);
}